// Round 1
// baseline (6501.941 us; speedup 1.0000x reference)
//
#include <hip/hip_runtime.h>
#include <math.h>

// Problem dims
#define TT 100
#define BB 64
#define II 256
#define HH 512
// derived
#define G4H 2048   // 4H
#define G3H 1536   // 3H

// ---- workspace layout (float offsets) ----
// G_T   [T][4H][B]  gates from x@Wih^T + biases, layout [t][j][b]
// Hbuf  [T+1][H][B] h history, transposed [t][k][b]; slot 0 = initial_h^T
// Fbuf  [T][H][B]   f gates
// Dbuf  [T][3H][B]  d values (later scaled in-place to \tilde{d})
// cT    [H][B]      running cell state transposed
// xT    [T][I][B]   input transposed
// WihT  [I][4H]
// WhhT  [H][4H]
#define OFF_GT    0
#define OFF_HBUF  13107200
#define OFF_FBUF  16416768
#define OFF_DBUF  19693568
#define OFF_CT    29523968
#define OFF_XT    29556736
#define OFF_WIHT  31195136
#define OFF_WHHT  31719424

// ---- output layout (float offsets in d_out) ----
#define O_OUT   0          // outputs [T][B][H]
#define O_CX    3276800    // cx [B][H]
#define O_EVIH  3309568    // ev_ih [B][3H][I]
#define O_EVHH  28475392   // ev_hh [B][3H][H]
#define O_EVB   78807040   // ev_b  [B][3H]

// Generic 64x64 tiled transpose: dst[c][r] = src[r][c]. R,C multiples of 64.
__global__ __launch_bounds__(256) void tp64(const float* __restrict__ src,
                                            float* __restrict__ dst,
                                            int R, int C,
                                            long sstride, long dstride) {
  __shared__ float tile[64][65];
  src += (long)blockIdx.z * sstride;
  dst += (long)blockIdx.z * dstride;
  int r0 = blockIdx.y * 64, c0 = blockIdx.x * 64;
  int tx = threadIdx.x & 15, tq = threadIdx.x >> 4;
#pragma unroll
  for (int p = 0; p < 4; ++p) {
    int rl = p * 16 + tq;
    float4 v = *(const float4*)(src + (long)(r0 + rl) * C + c0 + tx * 4);
    tile[rl][tx * 4 + 0] = v.x; tile[rl][tx * 4 + 1] = v.y;
    tile[rl][tx * 4 + 2] = v.z; tile[rl][tx * 4 + 3] = v.w;
  }
  __syncthreads();
#pragma unroll
  for (int p = 0; p < 4; ++p) {
    int cl = p * 16 + tq;
    float4 v;
    v.x = tile[tx * 4 + 0][cl]; v.y = tile[tx * 4 + 1][cl];
    v.z = tile[tx * 4 + 2][cl]; v.w = tile[tx * 4 + 3][cl];
    *(float4*)(dst + (long)(c0 + cl) * R + r0 + tx * 4) = v;
  }
}

// G_T[t][j][b] = bias_ih[j] + bias_hh[j] + sum_k x[t][b][k] * Wih[j][k]
// wave-per-4j, lane = b; W via scalar loads, x via coalesced vector loads.
__global__ __launch_bounds__(256) void gemm_gx(const float* __restrict__ xT,
                                               const float* __restrict__ WihT,
                                               const float* __restrict__ b_ih,
                                               const float* __restrict__ b_hh,
                                               float* __restrict__ G_T) {
  int t = blockIdx.y;
  int lane = threadIdx.x & 63;
  int wave = __builtin_amdgcn_readfirstlane(threadIdx.x >> 6);
  int j0 = blockIdx.x * 16 + wave * 4;
  float acc[4];
#pragma unroll
  for (int q = 0; q < 4; ++q) acc[q] = b_ih[j0 + q] + b_hh[j0 + q];
  const float* xp = xT + t * (II * BB) + lane;
  const float* wp = WihT + j0;
#pragma unroll 4
  for (int k = 0; k < II; ++k) {
    float h = xp[k * BB];
#pragma unroll
    for (int q = 0; q < 4; ++q) acc[q] = fmaf(wp[k * G4H + q], h, acc[q]);
  }
  float* gp = G_T + t * (G4H * BB) + j0 * BB + lane;
#pragma unroll
  for (int q = 0; q < 4; ++q) gp[q * BB] = acc[q];
}

// One LSTM step: gates = G_T[t] + h_{t-1} @ Whh^T, pointwise, store f/d/h/c.
// wave handles one hh (all 4 gates), lane = b.
__global__ __launch_bounds__(128) void lstm_step(const float* __restrict__ G_T,
                                                 const float* __restrict__ WhhT,
                                                 float* __restrict__ Hbuf,
                                                 float* __restrict__ cT,
                                                 float* __restrict__ Fbuf,
                                                 float* __restrict__ Dbuf,
                                                 int t) {
  int lane = threadIdx.x & 63;
  int wave = __builtin_amdgcn_readfirstlane(threadIdx.x >> 6);
  int hh = blockIdx.x * 2 + wave;
  float acc[4];
  const float* gp = G_T + t * (G4H * BB) + hh * BB + lane;
#pragma unroll
  for (int q = 0; q < 4; ++q) acc[q] = gp[q * (HH * BB)];
  const float* hp = Hbuf + t * (HH * BB) + lane;
  const float* wp = WhhT + hh;
#pragma unroll 4
  for (int k = 0; k < HH; ++k) {
    float h = hp[k * BB];
#pragma unroll
    for (int q = 0; q < 4; ++q) acc[q] = fmaf(wp[k * G4H + q * HH], h, acc[q]);
  }
  float ig = 1.f / (1.f + expf(-acc[0]));
  float fg = 1.f / (1.f + expf(-acc[1]));
  float gg = tanhf(acc[2]);
  float og = 1.f / (1.f + expf(-acc[3]));
  int idx = hh * BB + lane;
  float co = cT[idx];
  float cy = fg * co + ig * gg;
  cT[idx] = cy;
  Hbuf[(t + 1) * (HH * BB) + idx] = og * tanhf(cy);
  Fbuf[t * (HH * BB) + idx] = fg;
  float* dp = Dbuf + t * (G3H * BB) + idx;
  dp[0] = gg * ig * (1.f - ig);            // d_i
  dp[HH * BB] = co * fg * (1.f - fg);      // d_f
  dp[2 * HH * BB] = ig * (1.f - gg * gg);  // d_g
}

// Backward suffix scan: Dbuf[t] *= P_t (P_{T-1}=1, P_t = P_{t+1}*f_{t+1});
// also emits ev_b = sum_t scaled d.
__global__ __launch_bounds__(256) void suffix_scale(float* __restrict__ Dbuf,
                                                    const float* __restrict__ Fbuf,
                                                    float* __restrict__ evb) {
  int g = blockIdx.x * 256 + threadIdx.x;
  int b = g & 63, hh = g >> 6;
  float P = 1.f, e0 = 0.f, e1 = 0.f, e2 = 0.f;
  for (int t = TT - 1; t >= 0; --t) {
    float* dp = Dbuf + t * (G3H * BB) + hh * BB + b;
    float v0 = dp[0] * P, v1 = dp[HH * BB] * P, v2 = dp[2 * HH * BB] * P;
    dp[0] = v0; dp[HH * BB] = v1; dp[2 * HH * BB] = v2;
    e0 += v0; e1 += v1; e2 += v2;
    P *= Fbuf[t * (HH * BB) + hh * BB + b];
  }
  evb[b * G3H + hh] = e0;
  evb[b * G3H + HH + hh] = e1;
  evb[b * G3H + 2 * HH + hh] = e2;
}

// ev_ih[b][j][i] = sum_t Dbuf~[t][j][b] * x[t][b][i]
__global__ __launch_bounds__(256) void ev_ih_gemm(const float* __restrict__ x,
                                                  const float* __restrict__ Dbuf,
                                                  float* __restrict__ out) {
  int b = blockIdx.y;
  int j0 = blockIdx.x * 16;
  int i = threadIdx.x;
  float acc[16] = {};
#pragma unroll 2
  for (int t = 0; t < TT; ++t) {
    float z = x[t * (BB * II) + b * II + i];
    const float* ap = Dbuf + t * (G3H * BB) + j0 * BB + b;
#pragma unroll
    for (int jj = 0; jj < 16; ++jj) acc[jj] = fmaf(ap[jj * BB], z, acc[jj]);
  }
  float* op = out + (long)b * (G3H * II) + j0 * II + i;
#pragma unroll
  for (int jj = 0; jj < 16; ++jj) op[jj * II] = acc[jj];
}

// ev_hh[b][j][k] = sum_t Dbuf~[t][j][b] * h_{t-1}[b][k]
// h_{t-1}: t==0 -> initial_h, else outputs[t-1] (already in d_out).
__global__ __launch_bounds__(256) void ev_hh_gemm(const float* __restrict__ h0,
                                                  const float* __restrict__ outs,
                                                  const float* __restrict__ Dbuf,
                                                  float* __restrict__ out) {
  int b = blockIdx.y;
  int j0 = blockIdx.x * 16;
  int i = threadIdx.x;
  float acc0[16] = {}, acc1[16] = {};
  for (int t = 0; t < TT; ++t) {
    const float* zp = (t == 0) ? (h0 + b * HH) : (outs + (t - 1) * (BB * HH) + b * HH);
    float z0 = zp[i], z1 = zp[i + 256];
    const float* ap = Dbuf + t * (G3H * BB) + j0 * BB + b;
#pragma unroll
    for (int jj = 0; jj < 16; ++jj) {
      float w = ap[jj * BB];
      acc0[jj] = fmaf(w, z0, acc0[jj]);
      acc1[jj] = fmaf(w, z1, acc1[jj]);
    }
  }
  float* op = out + (long)b * (G3H * HH) + j0 * HH + i;
#pragma unroll
  for (int jj = 0; jj < 16; ++jj) {
    op[jj * HH] = acc0[jj];
    op[jj * HH + 256] = acc1[jj];
  }
}

extern "C" void kernel_launch(void* const* d_in, const int* in_sizes, int n_in,
                              void* d_out, int out_size, void* d_ws, size_t ws_size,
                              hipStream_t stream) {
  const float* x    = (const float*)d_in[0];  // [T][B][I]
  const float* h0   = (const float*)d_in[1];  // [B][H]
  const float* c0   = (const float*)d_in[2];  // [B][H]
  const float* Wih  = (const float*)d_in[3];  // [4H][I]
  const float* Whh  = (const float*)d_in[4];  // [4H][H]
  const float* bih  = (const float*)d_in[5];
  const float* bhh  = (const float*)d_in[6];
  float* out = (float*)d_out;
  float* ws = (float*)d_ws;

  float* G_T  = ws + OFF_GT;
  float* Hbuf = ws + OFF_HBUF;
  float* Fbuf = ws + OFF_FBUF;
  float* Dbuf = ws + OFF_DBUF;
  float* cT   = ws + OFF_CT;
  float* xT   = ws + OFF_XT;
  float* WihT = ws + OFF_WIHT;
  float* WhhT = ws + OFF_WHHT;

  // transposes
  tp64<<<dim3(II / 64, G4H / 64, 1), 256, 0, stream>>>(Wih, WihT, G4H, II, 0, 0);
  tp64<<<dim3(HH / 64, G4H / 64, 1), 256, 0, stream>>>(Whh, WhhT, G4H, HH, 0, 0);
  tp64<<<dim3(II / 64, 1, TT), 256, 0, stream>>>(x, xT, BB, II, BB * II, BB * II);
  tp64<<<dim3(HH / 64, 1, 1), 256, 0, stream>>>(h0, Hbuf, BB, HH, 0, 0);
  tp64<<<dim3(HH / 64, 1, 1), 256, 0, stream>>>(c0, cT, BB, HH, 0, 0);

  // big parallel GEMM: x @ Wih^T + biases
  gemm_gx<<<dim3(G4H / 16, TT, 1), 256, 0, stream>>>(xT, WihT, bih, bhh, G_T);

  // sequential recurrence
  for (int t = 0; t < TT; ++t) {
    lstm_step<<<dim3(HH / 2, 1, 1), 128, 0, stream>>>(G_T, WhhT, Hbuf, cT, Fbuf, Dbuf, t);
  }

  // backward suffix scaling (+ ev_b)
  suffix_scale<<<dim3(HH * BB / 256, 1, 1), 256, 0, stream>>>(Dbuf, Fbuf, out + O_EVB);

  // outputs + cx (transpose back)
  tp64<<<dim3(1, HH / 64, TT), 256, 0, stream>>>(Hbuf + HH * BB, out + O_OUT,
                                                 HH, BB, HH * BB, HH * BB);
  tp64<<<dim3(1, HH / 64, 1), 256, 0, stream>>>(cT, out + O_CX, HH, BB, 0, 0);

  // final trace GEMMs
  ev_ih_gemm<<<dim3(G3H / 16, BB, 1), 256, 0, stream>>>(x, Dbuf, out + O_EVIH);
  ev_hh_gemm<<<dim3(G3H / 16, BB, 1), 256, 0, stream>>>(h0, out + O_OUT, Dbuf, out + O_EVHH);
}

// Round 2
// 1768.211 us; speedup vs baseline: 3.6771x; 3.6771x over previous
//
#include <hip/hip_runtime.h>
#include <math.h>

// Problem dims
#define TT 100
#define BB 64
#define II 256
#define HH 512
#define G4H 2048   // 4H
#define G3H 1536   // 3H

// ---- workspace layout (float offsets) ----
// G_T   [T][4H][B]   gates from x@Wih^T + biases, layout [t][j][b]
// DbufT [B][T][3H]   (aliases G_T region after step loop — G_T dead by then)
// Hbuf  [T+1][H][B]  h history transposed; slot 0 = initial_h^T
// Fbuf  [T][H][B]    f gates
// Dbuf  [T][3H][B]   d values (scaled in-place to \tilde{d})
// cT    [H][B]
// xT    [T][I][B]    (WhhG aliases xT region after gx GEMM — xT dead by then)
// WihT  [I][4H]
// WhhT  [H][4H]
#define OFF_GT    0
#define OFF_HBUF  13107200
#define OFF_FBUF  16416768
#define OFF_DBUF  19693568
#define OFF_CT    29523968
#define OFF_XT    29556736
#define OFF_WIHT  31195136
#define OFF_WHHT  31719424

// ---- output layout (float offsets in d_out) ----
#define O_OUT   0          // outputs [T][B][H]
#define O_CX    3276800    // cx [B][H]
#define O_EVIH  3309568    // ev_ih [B][3H][I]
#define O_EVHH  28475392   // ev_hh [B][3H][H]
#define O_EVB   78807040   // ev_b  [B][3H]

// Generic 64x64 tiled transpose: dst[c][r] = src[r][c]. R,C multiples of 64.
__global__ __launch_bounds__(256) void tp64(const float* __restrict__ src,
                                            float* __restrict__ dst,
                                            int R, int C,
                                            long sstride, long dstride) {
  __shared__ float tile[64][65];
  src += (long)blockIdx.z * sstride;
  dst += (long)blockIdx.z * dstride;
  int r0 = blockIdx.y * 64, c0 = blockIdx.x * 64;
  int tx = threadIdx.x & 15, tq = threadIdx.x >> 4;
#pragma unroll
  for (int p = 0; p < 4; ++p) {
    int rl = p * 16 + tq;
    float4 v = *(const float4*)(src + (long)(r0 + rl) * C + c0 + tx * 4);
    tile[rl][tx * 4 + 0] = v.x; tile[rl][tx * 4 + 1] = v.y;
    tile[rl][tx * 4 + 2] = v.z; tile[rl][tx * 4 + 3] = v.w;
  }
  __syncthreads();
#pragma unroll
  for (int p = 0; p < 4; ++p) {
    int cl = p * 16 + tq;
    float4 v;
    v.x = tile[tx * 4 + 0][cl]; v.y = tile[tx * 4 + 1][cl];
    v.z = tile[tx * 4 + 2][cl]; v.w = tile[tx * 4 + 3][cl];
    *(float4*)(dst + (long)(c0 + cl) * R + r0 + tx * 4) = v;
  }
}

// WhhG[k][hh*4+g] = WhhT[k][g*512+hh]  (gate-interleaved for s_load_dwordx4)
__global__ __launch_bounds__(256) void make_whhg(const float* __restrict__ WhhT,
                                                 float* __restrict__ WhhG) {
  int gid = blockIdx.x * 256 + threadIdx.x;  // 512*2048 total
  int k = gid >> 11, j = gid & 2047;
  float v = WhhT[gid];
  WhhG[(long)k * G4H + ((j & 511) << 2) + (j >> 9)] = v;
}

// Tiled TN GEMM: C[m][n] = sum_k A[k][m] * Z[k][n]  (+ bias[m] if BIAS).
// Both operands stored K-major. 64x64 C-tile, 256 thr, 4x4 outputs/thread.
// ZSHIFT: Z row k maps to (k==0 ? Z0 : Z + (k-1)*ldz)  [for h_{t-1} history].
template <int BK, int KTILES, bool BIAS, bool ZSHIFT>
__global__ __launch_bounds__(256) void gemm_tn(
    const float* __restrict__ A, long batchA, int lda,
    const float* __restrict__ Z, long batchZ, int ldz,
    const float* __restrict__ Z0, long batchZ0,
    float* __restrict__ C, long batchC, int ldc,
    const float* __restrict__ bia, const float* __restrict__ bib) {
  __shared__ float As[BK][64];
  __shared__ float Zs[BK][64];
  int tid = threadIdx.x;
  int tn = tid & 15, tm = tid >> 4;
  int m0 = blockIdx.x * 64, n0 = blockIdx.y * 64;
  long bz = blockIdx.z;
  const float* Ab = A + bz * batchA + m0;
  const float* Zb = Z + bz * batchZ + n0;
  const float* Z0b = ZSHIFT ? (Z0 + bz * batchZ0 + n0) : nullptr;
  float acc[4][4] = {};
  for (int kt = 0; kt < KTILES; ++kt) {
    int k0 = kt * BK;
#pragma unroll
    for (int p = tid; p < BK * 64; p += 256) {
      int r = p >> 6, c = p & 63;
      int k = k0 + r;
      As[r][c] = Ab[(long)k * lda + c];
      const float* zr;
      if (ZSHIFT)
        zr = (k == 0) ? Z0b : (Zb + (long)(k - 1) * ldz);
      else
        zr = Zb + (long)k * ldz;
      Zs[r][c] = zr[c];
    }
    __syncthreads();
#pragma unroll 4
    for (int kk = 0; kk < BK; ++kk) {
      float4 a = *(const float4*)&As[kk][tm * 4];
      float4 z = *(const float4*)&Zs[kk][tn * 4];
      float av[4] = {a.x, a.y, a.z, a.w};
      float zv[4] = {z.x, z.y, z.z, z.w};
#pragma unroll
      for (int q = 0; q < 4; ++q)
#pragma unroll
        for (int r = 0; r < 4; ++r)
          acc[q][r] = fmaf(av[q], zv[r], acc[q][r]);
    }
    __syncthreads();
  }
  float* Cb = C + bz * batchC + n0 + tn * 4;
#pragma unroll
  for (int q = 0; q < 4; ++q) {
    int m = m0 + tm * 4 + q;
    float bv = BIAS ? (bia[m] + bib[m]) : 0.f;
    float4 v;
    v.x = acc[q][0] + bv; v.y = acc[q][1] + bv;
    v.z = acc[q][2] + bv; v.w = acc[q][3] + bv;
    *(float4*)(Cb + (long)m * ldc) = v;
  }
}

// One LSTM step. Block = 512 thr = 8 waves, handles 2 hh.
// Wave w: hh_local = w&1, k-part = w>>1 (128 k each); lane = b.
// Gate-interleaved WhhG gives one uniform dwordx4 per k.
__global__ __launch_bounds__(512) void lstm_step2(const float* __restrict__ G_T,
                                                  const float* __restrict__ WhhG,
                                                  float* __restrict__ Hbuf,
                                                  float* __restrict__ cT,
                                                  float* __restrict__ Fbuf,
                                                  float* __restrict__ Dbuf,
                                                  int t) {
  __shared__ float red[2][4][4][64];  // [hh_local][kpart][gate][b]
  int tid = threadIdx.x;
  int lane = tid & 63;
  int wave = __builtin_amdgcn_readfirstlane(tid >> 6);  // 0..7, wave-uniform
  int hl = wave & 1, kp = wave >> 1;
  int hh = blockIdx.x * 2 + hl;
  float a0 = 0.f, a1 = 0.f, a2 = 0.f, a3 = 0.f;
  const float* hp = Hbuf + (long)t * (HH * BB) + kp * 128 * BB + lane;
  const float* wp = WhhG + (long)(kp * 128) * G4H + hh * 4;
#pragma unroll 4
  for (int k = 0; k < 128; ++k) {
    float h = hp[(long)k * BB];
    float4 w = *(const float4*)(wp + (long)k * G4H);
    a0 = fmaf(w.x, h, a0);
    a1 = fmaf(w.y, h, a1);
    a2 = fmaf(w.z, h, a2);
    a3 = fmaf(w.w, h, a3);
  }
  red[hl][kp][0][lane] = a0;
  red[hl][kp][1][lane] = a1;
  red[hl][kp][2][lane] = a2;
  red[hl][kp][3][lane] = a3;
  __syncthreads();
  if (tid < 128) {
    int b = tid & 63, h2 = tid >> 6;
    int hhx = blockIdx.x * 2 + h2;
    const float* gp = G_T + (long)t * (G4H * BB) + hhx * BB + b;
    float g[4];
#pragma unroll
    for (int q = 0; q < 4; ++q)
      g[q] = gp[(long)q * (HH * BB)] + red[h2][0][q][b] + red[h2][1][q][b] +
             red[h2][2][q][b] + red[h2][3][q][b];
    float ig = 1.f / (1.f + expf(-g[0]));
    float fg = 1.f / (1.f + expf(-g[1]));
    float gg = tanhf(g[2]);
    float og = 1.f / (1.f + expf(-g[3]));
    int idx = hhx * BB + b;
    float co = cT[idx];
    float cy = fg * co + ig * gg;
    cT[idx] = cy;
    Hbuf[(long)(t + 1) * (HH * BB) + idx] = og * tanhf(cy);
    Fbuf[(long)t * (HH * BB) + idx] = fg;
    float* dp = Dbuf + (long)t * (G3H * BB) + idx;
    dp[0] = gg * ig * (1.f - ig);
    dp[HH * BB] = co * fg * (1.f - fg);
    dp[2 * HH * BB] = ig * (1.f - gg * gg);
  }
}

// Backward suffix scan: Dbuf[t] *= P_t; also emits ev_b.
__global__ __launch_bounds__(256) void suffix_scale(float* __restrict__ Dbuf,
                                                    const float* __restrict__ Fbuf,
                                                    float* __restrict__ evb) {
  int g = blockIdx.x * 256 + threadIdx.x;
  int b = g & 63, hh = g >> 6;
  float P = 1.f, e0 = 0.f, e1 = 0.f, e2 = 0.f;
#pragma unroll 2
  for (int t = TT - 1; t >= 0; --t) {
    float* dp = Dbuf + (long)t * (G3H * BB) + hh * BB + b;
    float v0 = dp[0] * P, v1 = dp[HH * BB] * P, v2 = dp[2 * HH * BB] * P;
    dp[0] = v0; dp[HH * BB] = v1; dp[2 * HH * BB] = v2;
    e0 += v0; e1 += v1; e2 += v2;
    P *= Fbuf[(long)t * (HH * BB) + hh * BB + b];
  }
  evb[b * G3H + hh] = e0;
  evb[b * G3H + HH + hh] = e1;
  evb[b * G3H + 2 * HH + hh] = e2;
}

extern "C" void kernel_launch(void* const* d_in, const int* in_sizes, int n_in,
                              void* d_out, int out_size, void* d_ws, size_t ws_size,
                              hipStream_t stream) {
  const float* x   = (const float*)d_in[0];  // [T][B][I]
  const float* h0  = (const float*)d_in[1];  // [B][H]
  const float* c0  = (const float*)d_in[2];  // [B][H]
  const float* Wih = (const float*)d_in[3];  // [4H][I]
  const float* Whh = (const float*)d_in[4];  // [4H][H]
  const float* bih = (const float*)d_in[5];
  const float* bhh = (const float*)d_in[6];
  float* out = (float*)d_out;
  float* ws = (float*)d_ws;

  float* G_T   = ws + OFF_GT;
  float* DbufT = ws + OFF_GT;    // aliases G_T (G_T dead after step loop)
  float* Hbuf  = ws + OFF_HBUF;
  float* Fbuf  = ws + OFF_FBUF;
  float* Dbuf  = ws + OFF_DBUF;
  float* cT    = ws + OFF_CT;
  float* xT    = ws + OFF_XT;
  float* WhhG  = ws + OFF_XT;    // aliases xT (xT dead after gx GEMM)
  float* WihT  = ws + OFF_WIHT;
  float* WhhT  = ws + OFF_WHHT;

  // ---- prep transposes ----
  tp64<<<dim3(II / 64, G4H / 64, 1), 256, 0, stream>>>(Wih, WihT, G4H, II, 0, 0);
  tp64<<<dim3(HH / 64, G4H / 64, 1), 256, 0, stream>>>(Whh, WhhT, G4H, HH, 0, 0);
  tp64<<<dim3(II / 64, 1, TT), 256, 0, stream>>>(x, xT, BB, II, BB * II, BB * II);
  tp64<<<dim3(HH / 64, 1, 1), 256, 0, stream>>>(h0, Hbuf, BB, HH, 0, 0);
  tp64<<<dim3(HH / 64, 1, 1), 256, 0, stream>>>(c0, cT, BB, HH, 0, 0);

  // ---- G = x @ Wih^T + biases, layout [t][j][b] ----
  // C[m=j 2048][n=b 64] = sum_k WihT[k][j] * xT[t][k][b], K=256
  gemm_tn<64, 4, true, false><<<dim3(G4H / 64, 1, TT), 256, 0, stream>>>(
      WihT, 0, G4H, xT, (long)II * BB, BB, nullptr, 0,
      G_T, (long)G4H * BB, BB, bih, bhh);

  // ---- gate-interleave Whh (after gx: WhhG overwrites xT) ----
  make_whhg<<<dim3(HH * G4H / 256, 1, 1), 256, 0, stream>>>(WhhT, WhhG);

  // ---- sequential recurrence ----
  for (int t = 0; t < TT; ++t) {
    lstm_step2<<<dim3(HH / 2, 1, 1), 512, 0, stream>>>(G_T, WhhG, Hbuf, cT,
                                                       Fbuf, Dbuf, t);
  }

  // ---- backward suffix scaling (+ ev_b) ----
  suffix_scale<<<dim3(HH * BB / 256, 1, 1), 256, 0, stream>>>(Dbuf, Fbuf,
                                                              out + O_EVB);

  // ---- Dbuf [T*3H][B] -> DbufT [B][T*3H] (into dead G_T region) ----
  tp64<<<dim3(1, TT * G3H / 64, 1), 256, 0, stream>>>(Dbuf, DbufT, TT * G3H, BB,
                                                      0, 0);

  // ---- outputs + cx ----
  tp64<<<dim3(1, HH / 64, TT), 256, 0, stream>>>(Hbuf + HH * BB, out + O_OUT,
                                                 HH, BB, HH * BB, HH * BB);
  tp64<<<dim3(1, HH / 64, 1), 256, 0, stream>>>(cT, out + O_CX, HH, BB, 0, 0);

  // ---- ev_ih[b][j][i] = sum_t DbufT[b][t][j] * x[t][b][i], K=100 ----
  gemm_tn<20, 5, false, false><<<dim3(G3H / 64, II / 64, BB), 256, 0, stream>>>(
      DbufT, (long)TT * G3H, G3H, x, (long)II, (long)BB * II, nullptr, 0,
      out + O_EVIH, (long)G3H * II, II, nullptr, nullptr);

  // ---- ev_hh[b][j][k] = sum_t DbufT[b][t][j] * h_{t-1}[b][k], K=100 ----
  gemm_tn<20, 5, false, true><<<dim3(G3H / 64, HH / 64, BB), 256, 0, stream>>>(
      DbufT, (long)TT * G3H, G3H, out + O_OUT, (long)HH, (long)BB * HH,
      h0, (long)HH,
      out + O_EVHH, (long)G3H * HH, HH, nullptr, nullptr);
}